// Round 18
// baseline (318.293 us; speedup 1.0000x reference)
//
#include <hip/hip_runtime.h>
#include <cstdint>
#include <cstddef>

#define N_NODES 50000
#define N_EDGES 800000
#define ET (N_EDGES + N_NODES)   // edges + self loops
#define D 128
#define NLAYERS 3
#define LOG2E 1.44269504f
#define DEFER_THR 11.5415603f    // 8 nats in log2 units
#define NB_SCAN ((N_NODES + 1023) / 1024)   // 49 blocks
#define GEMM_BLOCKS (((N_NODES + 127) / 128) * 2)   // 782
#define SCAT_STRIDE (GEMM_BLOCKS * 256)             // 200192
#define EPT 5                                        // ceil(ET / SCAT_STRIDE)
#define BPAD 136                  // padded LDS row (2-way banks on b128 reads = free)

typedef __bf16 bf16x8 __attribute__((ext_vector_type(8)));
typedef float  f32x4  __attribute__((ext_vector_type(4)));
typedef float  f32x2  __attribute__((ext_vector_type(2)));

__device__ __forceinline__ unsigned short f2bf_rne(float v) {
    unsigned u = __float_as_uint(v);
    u += 0x7fffu + ((u >> 16) & 1u);
    return (unsigned short)(u >> 16);
}
__device__ __forceinline__ f32x2 unpack_bf2(unsigned u) {
    f32x2 r;
    r.x = __uint_as_float(u << 16);
    r.y = __uint_as_float(u & 0xffff0000u);
    return r;
}

// ===== merged prep: x -> bf16, transpose weights -> bf16, degree count ==============
__global__ void prep_kernel(const float* __restrict__ x,
                            const float* __restrict__ Wl,
                            const float* __restrict__ Wr,
                            const int* __restrict__ dstp,
                            unsigned short* __restrict__ hhi,
                            unsigned short* __restrict__ wlh,
                            unsigned short* __restrict__ wrh,
                            int* __restrict__ deg)
{
    int idx = blockIdx.x * blockDim.x + threadIdx.x;
    if (idx < (N_NODES * D) / 4) {
        float4 v = ((const float4*)x)[idx];
        uint2 hw;
        hw.x = (unsigned)f2bf_rne(v.x) | ((unsigned)f2bf_rne(v.y) << 16);
        hw.y = (unsigned)f2bf_rne(v.z) | ((unsigned)f2bf_rne(v.w) << 16);
        ((uint2*)hhi)[idx] = hw;
    }
    if (idx < NLAYERS * D * D) {
        int l   = idx / (D * D);
        int rem = idx - l * D * D;
        int kk  = rem / D;
        int nn  = rem - kk * D;
        int tp  = l * D * D + nn * D + kk;
        wlh[tp] = f2bf_rne(Wl[idx]);
        wrh[tp] = f2bf_rne(Wr[idx]);
    }
    if (idx < ET) {
        int dt = (idx < N_EDGES) ? dstp[idx] : idx - N_EDGES;
        atomicAdd(deg + dt, 1);
    }
}

// ================= CSR build ==================
__global__ void scan1_kernel(const int* __restrict__ deg,
                             int* __restrict__ incl, int* __restrict__ bsum)
{
    __shared__ int tmp[1024];
    int tid = threadIdx.x;
    int i = blockIdx.x * 1024 + tid;
    int v = (i < N_NODES) ? deg[i] : 0;
    tmp[tid] = v;
    __syncthreads();
    #pragma unroll
    for (int o = 1; o < 1024; o <<= 1) {
        int t = (tid >= o) ? tmp[tid - o] : 0;
        __syncthreads();
        tmp[tid] += t;
        __syncthreads();
    }
    if (i < N_NODES) incl[i] = tmp[tid];
    if (tid == 1023) bsum[blockIdx.x] = tmp[1023];
}

__global__ void scan3_kernel(const int* __restrict__ deg, const int* __restrict__ incl,
                             const int* __restrict__ bsum,
                             int* __restrict__ off, int* __restrict__ cursor,
                             unsigned short* __restrict__ esrc)
{
    __shared__ int sb[NB_SCAN + 1];
    int tid = threadIdx.x;
    if (tid < 64) {
        int v = (tid < NB_SCAN) ? bsum[tid] : 0;
        int orig = v;
        #pragma unroll
        for (int o = 1; o < 64; o <<= 1) {
            int t = __shfl_up(v, o, 64);
            if (tid >= o) v += t;
        }
        if (tid < NB_SCAN) sb[tid] = v - orig;   // exclusive
        if (tid == 63)     sb[NB_SCAN] = v;      // grand total
    }
    __syncthreads();
    if (blockIdx.x == 0 && tid < 32) esrc[ET + tid] = 0;   // pad (safe over-reads)
    int i = blockIdx.x * blockDim.x + tid;
    if (i < N_NODES) {
        int e = incl[i] - deg[i] + sb[i >> 10];
        off[i] = e;
        cursor[i] = e;
    } else if (i == N_NODES) {
        off[N_NODES] = sb[NB_SCAN];
    }
}

// ===== MFMA dual GEMM, 1-term bf16, LDS-staged B + fused two-phase CSR scatter =======
template <bool WITH_SCATTER>
__global__ __launch_bounds__(256, 4)
void gemm_mfma_kernel(const unsigned short* __restrict__ hhi,
                      const unsigned short* __restrict__ wlh,
                      const unsigned short* __restrict__ wrh,
                      const float* __restrict__ bl, const float* __restrict__ br,
                      const float* __restrict__ att,
                      unsigned short* __restrict__ xlb, unsigned short* __restrict__ xrb,
                      float* __restrict__ bs2,
                      const int* __restrict__ srcp, const int* __restrict__ dstp,
                      int* __restrict__ cursor, unsigned short* __restrict__ esrc, int n)
{
    __shared__ unsigned short lb[64][BPAD];   // 17 KiB
    __shared__ unsigned short rb[64][BPAD];   // 17 KiB

    int tid  = threadIdx.x;
    int lane = tid & 63;
    int wid  = tid >> 6;                  // 0..3
    int rowB = blockIdx.x >> 1;
    int half = blockIdx.x & 1;
    int c0   = half * 64;                 // column half
    int m0   = rowB * 128 + wid * 32;     // this wave's 32 rows
    int gl = lane & 15;
    int kg = lane >> 4;

    // ---- scatter prologue: issue edge loads early ----
    int es[EPT], ed[EPT];
    if (WITH_SCATTER) {
        #pragma unroll
        for (int j = 0; j < EPT; j++) {
            int e = blockIdx.x * 256 + tid + j * SCAT_STRIDE;
            if (e < N_EDGES)      { es[j] = srcp[e]; ed[j] = dstp[e]; }
            else if (e < ET)      { es[j] = e - N_EDGES; ed[j] = es[j]; }
            else                  { es[j] = -1; ed[j] = -1; }
        }
    }

    // ---- stage B half into LDS (coalesced 16B chunks) ----
    {
        const uint4* gl4 = (const uint4*)(wlh + (size_t)c0 * D);
        const uint4* gr4 = (const uint4*)(wrh + (size_t)c0 * D);
        #pragma unroll
        for (int c = 0; c < 4; c++) {
            int idx = c * 256 + tid;
            int row = idx >> 4;
            int kc  = idx & 15;
            *(uint4*)&lb[row][kc * 8] = gl4[idx];
            *(uint4*)&rb[row][kc * 8] = gr4[idx];
        }
    }
    __syncthreads();

    float blc[4], brc[4], attc[4];
    #pragma unroll
    for (int t = 0; t < 4; t++) {
        blc[t]  = bl [c0 + t * 16 + gl];
        brc[t]  = br [c0 + t * 16 + gl];
        attc[t] = att[c0 + t * 16 + gl];
    }

    int ar0 = m0 + gl;      if (ar0 >= n) ar0 = n - 1;
    int ar1 = m0 + 16 + gl; if (ar1 >= n) ar1 = n - 1;
    const unsigned short* ah0 = hhi + (size_t)ar0 * D + kg * 8;
    const unsigned short* ah1 = hhi + (size_t)ar1 * D + kg * 8;

    bf16x8 Ah0[4], Ah1[4];
    #pragma unroll
    for (int ks = 0; ks < 4; ks++) {
        Ah0[ks] = *(const bf16x8*)(ah0 + ks * 32);
        Ah1[ks] = *(const bf16x8*)(ah1 + ks * 32);
    }

    f32x4 accl[2][4], accr[2][4];
    #pragma unroll
    for (int rt = 0; rt < 2; rt++)
        #pragma unroll
        for (int t = 0; t < 4; t++) {
            accl[rt][t] = (f32x4){0.f, 0.f, 0.f, 0.f};
            accr[rt][t] = (f32x4){0.f, 0.f, 0.f, 0.f};
        }

    #pragma unroll
    for (int ks = 0; ks < 4; ks++) {
        #pragma unroll
        for (int t = 0; t < 4; t++) {
            int brow = t * 16 + gl;
            int kofs = kg * 8 + ks * 32;
            bf16x8 bLH = *(const bf16x8*)&lb[brow][kofs];
            bf16x8 bRH = *(const bf16x8*)&rb[brow][kofs];
            accl[0][t] = __builtin_amdgcn_mfma_f32_16x16x32_bf16(Ah0[ks], bLH, accl[0][t], 0, 0, 0);
            accr[0][t] = __builtin_amdgcn_mfma_f32_16x16x32_bf16(Ah0[ks], bRH, accr[0][t], 0, 0, 0);
            accl[1][t] = __builtin_amdgcn_mfma_f32_16x16x32_bf16(Ah1[ks], bLH, accl[1][t], 0, 0, 0);
            accr[1][t] = __builtin_amdgcn_mfma_f32_16x16x32_bf16(Ah1[ks], bRH, accr[1][t], 0, 0, 0);
        }
    }

    // ---- scatter phase A: issue all independent atomics ----
    int pos[EPT];
    if (WITH_SCATTER) {
        #pragma unroll
        for (int j = 0; j < EPT; j++)
            if (ed[j] >= 0) pos[j] = atomicAdd(cursor + ed[j], 1);
    }

    // ---- epilogue (C/D: col = lane&15, row = (lane>>4)*4 + reg) + bs half store ----
    #pragma unroll
    for (int rt = 0; rt < 2; rt++) {
        #pragma unroll
        for (int r = 0; r < 4; r++) {
            int row = m0 + rt * 16 + kg * 4 + r;
            if (row < n) {
                float p = 0.f;
                #pragma unroll
                for (int t = 0; t < 4; t++) {
                    int col = c0 + t * 16 + gl;
                    float vl = accl[rt][t][r] + blc[t];
                    xlb[(size_t)row * D + col] = f2bf_rne(vl);
                    xrb[(size_t)row * D + col] = f2bf_rne(accr[rt][t][r] + brc[t]);
                    p = fmaf(attc[t], vl, p);
                }
                p += __shfl_xor(p, 1, 64);
                p += __shfl_xor(p, 2, 64);
                p += __shfl_xor(p, 4, 64);
                p += __shfl_xor(p, 8, 64);
                if (gl == 0) bs2[row * 2 + half] = 0.6f * LOG2E * p;
            }
        }
    }

    // ---- scatter phase B: dependent esrc stores ----
    if (WITH_SCATTER) {
        #pragma unroll
        for (int j = 0; j < EPT; j++)
            if (ed[j] >= 0) esrc[pos[j]] = (unsigned short)es[j];
    }
}

// ===== fused per-node GATv2: 16 lanes/edge, 2 edges/group/iter, DEPTH-2 pipeline =====
// score = bs2[s].x + bs2[s].y + sum(aav*|xl_s+xr_d|),  aav pre-scaled by 0.4*LOG2E.
#define LOADSLOT(X4A, X4B, BSA, BSB, VA, VB, BASE)                         \
    {   int ka_ = (BASE) + g, kb_ = (BASE) + 4 + g;                        \
        VA = ka_ < kEnd; VB = kb_ < kEnd;                                  \
        int sa_ = esrc[ka_];                                               \
        int sb_ = esrc[kb_];                                               \
        X4A = *(const uint4*)(xlb + (size_t)sa_ * D + fb);                 \
        X4B = *(const uint4*)(xlb + (size_t)sb_ * D + fb);                 \
        float2 ta_ = *(const float2*)(bs2 + sa_ * 2);                      \
        float2 tb_ = *(const float2*)(bs2 + sb_ * 2);                      \
        BSA = ta_.x + ta_.y; BSB = tb_.x + tb_.y;  }

#define COMPUTE_SLOT(X4A, X4B, BSA, BSB, VA, VB)                           \
    {   f32x2 xa2[4], xb2[4];                                              \
        xa2[0] = unpack_bf2(X4A.x); xa2[1] = unpack_bf2(X4A.y);            \
        xa2[2] = unpack_bf2(X4A.z); xa2[3] = unpack_bf2(X4A.w);            \
        xb2[0] = unpack_bf2(X4B.x); xb2[1] = unpack_bf2(X4B.y);            \
        xb2[2] = unpack_bf2(X4B.z); xb2[3] = unpack_bf2(X4B.w);            \
        float s2a = 0.f, s2b = 0.f;                                        \
        _Pragma("unroll")                                                  \
        for (int q = 0; q < 4; q++) {                                      \
            f32x2 ta = xa2[q] + rr2[q];                                    \
            f32x2 tb = xb2[q] + rr2[q];                                    \
            s2a = fmaf(aav[2*q],   fabsf(ta.x), s2a);                      \
            s2a = fmaf(aav[2*q+1], fabsf(ta.y), s2a);                      \
            s2b = fmaf(aav[2*q],   fabsf(tb.x), s2b);                      \
            s2b = fmaf(aav[2*q+1], fabsf(tb.y), s2b);                      \
        }                                                                  \
        s2a += __shfl_xor(s2a, 1, 64);  s2b += __shfl_xor(s2b, 1, 64);     \
        s2a += __shfl_xor(s2a, 2, 64);  s2b += __shfl_xor(s2b, 2, 64);     \
        s2a += __shfl_xor(s2a, 4, 64);  s2b += __shfl_xor(s2b, 4, 64);     \
        s2a += __shfl_xor(s2a, 8, 64);  s2b += __shfl_xor(s2b, 8, 64);     \
        float sca = BSA + s2a;                                             \
        float scb = BSB + s2b;                                             \
        float mx2 = fmaxf(sca, scb);                                       \
        if (__any(mx2 > m + DEFER_THR)) {                                  \
            float mn = fmaxf(m, mx2);                                      \
            float f  = exp2f(m - mn);                                      \
            float pa = VA ? exp2f(sca - mn) : 0.f;                         \
            float pb = VB ? exp2f(scb - mn) : 0.f;                         \
            l = l * f + pa + pb;                                           \
            f32x2 fv = {f, f}, pa2 = {pa, pa}, pb2 = {pb, pb};             \
            _Pragma("unroll")                                              \
            for (int q = 0; q < 4; q++)                                    \
                acc2[q] = __builtin_elementwise_fma(acc2[q], fv,           \
                          __builtin_elementwise_fma(xa2[q], pa2, xb2[q] * pb2)); \
            m = mn;                                                        \
        } else {                                                           \
            float pa = VA ? exp2f(sca - m) : 0.f;                          \
            float pb = VB ? exp2f(scb - m) : 0.f;                          \
            l += pa + pb;                                                  \
            f32x2 pa2 = {pa, pa}, pb2 = {pb, pb};                          \
            _Pragma("unroll")                                              \
            for (int q = 0; q < 4; q++)                                    \
                acc2[q] = __builtin_elementwise_fma(xa2[q], pa2,           \
                          __builtin_elementwise_fma(xb2[q], pb2, acc2[q])); \
        }  }

template <int LAST>
__global__ void node_attn_kernel(const unsigned short* __restrict__ xlb,
                                 const unsigned short* __restrict__ xrb,
                                 const float* __restrict__ bs2,
                                 const float* __restrict__ att,
                                 const float* __restrict__ bias,
                                 const int* __restrict__ off,
                                 const unsigned short* __restrict__ esrc,
                                 float* __restrict__ outF,
                                 unsigned short* __restrict__ hhi)
{
    int i    = (int)((blockIdx.x * (size_t)blockDim.x + threadIdx.x) >> 6);
    int lane = threadIdx.x & 63;
    if (i >= N_NODES) return;
    int g  = lane >> 4;     // edge-pair slot 0..3
    int gl = lane & 15;     // lane within group
    int fb = gl * 8;        // this lane's 8 features

    float aav[8];
    f32x2 rr2[4];
    {
        float4 a0 = *(const float4*)(att + fb);
        float4 a1 = *(const float4*)(att + fb + 4);
        const float s = 0.4f * LOG2E;
        aav[0] = s * a0.x; aav[1] = s * a0.y; aav[2] = s * a0.z; aav[3] = s * a0.w;
        aav[4] = s * a1.x; aav[5] = s * a1.y; aav[6] = s * a1.z; aav[7] = s * a1.w;
        uint4 r4 = *(const uint4*)(xrb + (size_t)i * D + fb);
        rr2[0] = unpack_bf2(r4.x); rr2[1] = unpack_bf2(r4.y);
        rr2[2] = unpack_bf2(r4.z); rr2[3] = unpack_bf2(r4.w);
    }

    float m = -1e30f, l = 0.f;
    f32x2 acc2[4];
    #pragma unroll
    for (int j = 0; j < 4; j++) acc2[j] = (f32x2){0.f, 0.f};

    int k    = off[i];
    int kEnd = off[i + 1];

    // depth-2 pipeline: slots S0 (base k) and S1 (base k+8) both in flight
    uint4 A0, B0, A1, B1;
    float bs0a, bs0b, bs1a, bs1b;
    bool v0a, v0b, v1a, v1b;
    LOADSLOT(A0, B0, bs0a, bs0b, v0a, v0b, k);
    LOADSLOT(A1, B1, bs1a, bs1b, v1a, v1b, k + 8);

    while (k < kEnd) {
        // prefetch replacement for S0 (base k+16) BEFORE computing S0
        uint4 nA = A0, nB = B0;
        float nsa = bs0a, nsb = bs0b;
        bool nva = false, nvb = false;
        if (k + 16 < kEnd) LOADSLOT(nA, nB, nsa, nsb, nva, nvb, k + 16);
        COMPUTE_SLOT(A0, B0, bs0a, bs0b, v0a, v0b);
        A0 = nA; B0 = nB; bs0a = nsa; bs0b = nsb; v0a = nva; v0b = nvb;
        k += 8;
        if (k >= kEnd) break;

        // prefetch replacement for S1 (base k+16) BEFORE computing S1
        nA = A1; nB = B1; nsa = bs1a; nsb = bs1b; nva = false; nvb = false;
        if (k + 16 < kEnd) LOADSLOT(nA, nB, nsa, nsb, nva, nvb, k + 16);
        COMPUTE_SLOT(A1, B1, bs1a, bs1b, v1a, v1b);
        A1 = nA; B1 = nB; bs1a = nsa; bs1b = nsb; v1a = nva; v1b = nvb;
        k += 8;
    }

    // merge the 4 groups' online-softmax states (xor 16, then 32), log2 units
    #pragma unroll
    for (int o = 16; o <= 32; o <<= 1) {
        float mo  = __shfl_xor(m, o, 64);
        float lo2 = __shfl_xor(l, o, 64);
        float mn  = fmaxf(m, mo);
        float f1  = exp2f(m - mn);
        float f2s = exp2f(mo - mn);
        l = l * f1 + lo2 * f2s;
        f32x2 f1v = {f1, f1}, f2v = {f2s, f2s};
        #pragma unroll
        for (int q = 0; q < 4; q++) {
            f32x2 ao;
            ao.x = __shfl_xor(acc2[q].x, o, 64);
            ao.y = __shfl_xor(acc2[q].y, o, 64);
            acc2[q] = __builtin_elementwise_fma(acc2[q], f1v, ao * f2v);
        }
        m = mn;
    }

    float inv = 1.f / (l + 1e-16f);
    float hv[8];
    {
        float4 b0 = *(const float4*)(bias + fb);
        float4 b1 = *(const float4*)(bias + fb + 4);
        float bb[8] = {b0.x, b0.y, b0.z, b0.w, b1.x, b1.y, b1.z, b1.w};
        #pragma unroll
        for (int q = 0; q < 4; q++) {
            hv[2*q]   = fmaxf(fmaf(acc2[q].x, inv, bb[2*q]),   0.f);
            hv[2*q+1] = fmaxf(fmaf(acc2[q].y, inv, bb[2*q+1]), 0.f);
        }
    }

    if (LAST) {
        float mx = hv[0];
        #pragma unroll
        for (int j = 1; j < 8; j++) mx = fmaxf(mx, hv[j]);
        mx = fmaxf(mx, __shfl_xor(mx, 1, 64));
        mx = fmaxf(mx, __shfl_xor(mx, 2, 64));
        mx = fmaxf(mx, __shfl_xor(mx, 4, 64));
        mx = fmaxf(mx, __shfl_xor(mx, 8, 64));
        float se = 0.f;
        #pragma unroll
        for (int j = 0; j < 8; j++) se += __expf(hv[j] - mx);
        se += __shfl_xor(se, 1, 64);
        se += __shfl_xor(se, 2, 64);
        se += __shfl_xor(se, 4, 64);
        se += __shfl_xor(se, 8, 64);
        float ls = logf(se) + mx;
        if (g == 0) {
            float4 o0 = make_float4(hv[0] - ls, hv[1] - ls, hv[2] - ls, hv[3] - ls);
            float4 o1 = make_float4(hv[4] - ls, hv[5] - ls, hv[6] - ls, hv[7] - ls);
            float* dst = outF + (size_t)i * D + fb;
            *(float4*)(dst)     = o0;
            *(float4*)(dst + 4) = o1;
        }
    } else {
        if (g == 0) {
            unsigned pk[4];
            #pragma unroll
            for (int j = 0; j < 4; j++) {
                pk[j] = (unsigned)f2bf_rne(hv[j * 2]) |
                        ((unsigned)f2bf_rne(hv[j * 2 + 1]) << 16);
            }
            unsigned short* dst = hhi + (size_t)i * D + fb;
            *(uint4*)dst = make_uint4(pk[0], pk[1], pk[2], pk[3]);
        }
    }
}

extern "C" void kernel_launch(void* const* d_in, const int* in_sizes, int n_in,
                              void* d_out, int out_size, void* d_ws, size_t ws_size,
                              hipStream_t stream)
{
    const float* x    = (const float*)d_in[0];
    const int*   ei   = (const int*)  d_in[1];
    const float* Wl   = (const float*)d_in[2];
    const float* bl   = (const float*)d_in[3];
    const float* Wr   = (const float*)d_in[4];
    const float* br   = (const float*)d_in[5];
    const float* att  = (const float*)d_in[6];
    const float* bias = (const float*)d_in[7];
    float* out = (float*)d_out;

    const int* srcp = ei;
    const int* dstp = ei + N_EDGES;

    const size_t ND = (size_t)N_NODES * D;
    const size_t WSZ = (size_t)NLAYERS * D * D;
    char* ws = (char*)d_ws;
    unsigned short* xlb = (unsigned short*)ws; ws += ND * sizeof(unsigned short);
    unsigned short* xrb = (unsigned short*)ws; ws += ND * sizeof(unsigned short);
    unsigned short* hhi = (unsigned short*)ws; ws += ND * sizeof(unsigned short);
    unsigned short* wlh = (unsigned short*)ws; ws += WSZ * sizeof(unsigned short);
    unsigned short* wrh = (unsigned short*)ws; ws += WSZ * sizeof(unsigned short);
    float* bs2  = (float*)ws; ws += (size_t)N_NODES * 2 * sizeof(float);
    int* deg    = (int*)ws;  ws += (size_t)N_NODES * sizeof(int);
    int* incl   = (int*)ws;  ws += (size_t)N_NODES * sizeof(int);
    int* off    = (int*)ws;  ws += (size_t)(N_NODES + 1) * sizeof(int);
    int* cursor = (int*)ws;  ws += (size_t)N_NODES * sizeof(int);
    int* bsum   = (int*)ws;  ws += (size_t)NB_SCAN * sizeof(int);
    unsigned short* esrc = (unsigned short*)ws; ws += ((size_t)ET + 32) * sizeof(unsigned short);

    const int prepGrid  = (int)((ND / 4 + 255) / 256);
    const int nodeGrid  = (N_NODES + 3) / 4;
    const int scan3Grid = (N_NODES + 1 + 255) / 256;

    hipMemsetAsync(deg, 0, (size_t)N_NODES * sizeof(int), stream);
    prep_kernel<<<prepGrid, 256, 0, stream>>>(x, Wl, Wr, dstp, hhi, wlh, wrh, deg);

    scan1_kernel<<<NB_SCAN, 1024, 0, stream>>>(deg, incl, bsum);
    scan3_kernel<<<scan3Grid, 256, 0, stream>>>(deg, incl, bsum, off, cursor, esrc);

    for (int l = 0; l < NLAYERS; l++) {
        size_t wOff = (size_t)l * D * D;
        if (l == 0) {
            gemm_mfma_kernel<true><<<GEMM_BLOCKS, 256, 0, stream>>>(
                hhi, wlh + wOff, wrh + wOff,
                bl + (size_t)l * D, br + (size_t)l * D, att + (size_t)l * D,
                xlb, xrb, bs2, srcp, dstp, cursor, esrc, N_NODES);
        } else {
            gemm_mfma_kernel<false><<<GEMM_BLOCKS, 256, 0, stream>>>(
                hhi, wlh + wOff, wrh + wOff,
                bl + (size_t)l * D, br + (size_t)l * D, att + (size_t)l * D,
                xlb, xrb, bs2, nullptr, nullptr, nullptr, nullptr, N_NODES);
        }

        if (l == NLAYERS - 1) {
            node_attn_kernel<1><<<nodeGrid, 256, 0, stream>>>(
                xlb, xrb, bs2, att + (size_t)l * D, bias + (size_t)l * D,
                off, esrc, out, nullptr);
        } else {
            node_attn_kernel<0><<<nodeGrid, 256, 0, stream>>>(
                xlb, xrb, bs2, att + (size_t)l * D, bias + (size_t)l * D,
                off, esrc, nullptr, hhi);
        }
    }
}

// Round 19
// 302.357 us; speedup vs baseline: 1.0527x; 1.0527x over previous
//
#include <hip/hip_runtime.h>
#include <cstdint>
#include <cstddef>

#define N_NODES 50000
#define N_EDGES 800000
#define ET (N_EDGES + N_NODES)   // edges + self loops
#define D 128
#define NLAYERS 3
#define LOG2E 1.44269504f
#define DEFER_THR 11.5415603f    // 8 nats in log2 units
#define NB_SCAN ((N_NODES + 1023) / 1024)   // 49 blocks
#define GEMM_BLOCKS (((N_NODES + 127) / 128) * 2)   // 782
#define SCAT_STRIDE (GEMM_BLOCKS * 256)             // 200192
#define EPT 5                                        // ceil(ET / SCAT_STRIDE)
#define BPAD 136                  // padded LDS row (2-way banks on b128 reads = free)

typedef __bf16 bf16x8 __attribute__((ext_vector_type(8)));
typedef float  f32x4  __attribute__((ext_vector_type(4)));
typedef float  f32x2  __attribute__((ext_vector_type(2)));

__device__ __forceinline__ unsigned short f2bf_rne(float v) {
    unsigned u = __float_as_uint(v);
    u += 0x7fffu + ((u >> 16) & 1u);
    return (unsigned short)(u >> 16);
}
__device__ __forceinline__ f32x2 unpack_bf2(unsigned u) {
    f32x2 r;
    r.x = __uint_as_float(u << 16);
    r.y = __uint_as_float(u & 0xffff0000u);
    return r;
}

// ===== merged prep: x -> bf16, transpose weights -> bf16, degree count ==============
__global__ void prep_kernel(const float* __restrict__ x,
                            const float* __restrict__ Wl,
                            const float* __restrict__ Wr,
                            const int* __restrict__ dstp,
                            unsigned short* __restrict__ hhi,
                            unsigned short* __restrict__ wlh,
                            unsigned short* __restrict__ wrh,
                            int* __restrict__ deg)
{
    int idx = blockIdx.x * blockDim.x + threadIdx.x;
    if (idx < (N_NODES * D) / 4) {
        float4 v = ((const float4*)x)[idx];
        uint2 hw;
        hw.x = (unsigned)f2bf_rne(v.x) | ((unsigned)f2bf_rne(v.y) << 16);
        hw.y = (unsigned)f2bf_rne(v.z) | ((unsigned)f2bf_rne(v.w) << 16);
        ((uint2*)hhi)[idx] = hw;
    }
    if (idx < NLAYERS * D * D) {
        int l   = idx / (D * D);
        int rem = idx - l * D * D;
        int kk  = rem / D;
        int nn  = rem - kk * D;
        int tp  = l * D * D + nn * D + kk;
        wlh[tp] = f2bf_rne(Wl[idx]);
        wrh[tp] = f2bf_rne(Wr[idx]);
    }
    if (idx < ET) {
        int dt = (idx < N_EDGES) ? dstp[idx] : idx - N_EDGES;
        atomicAdd(deg + dt, 1);
    }
}

// ================= CSR build ==================
__global__ void scan1_kernel(const int* __restrict__ deg,
                             int* __restrict__ incl, int* __restrict__ bsum)
{
    __shared__ int tmp[1024];
    int tid = threadIdx.x;
    int i = blockIdx.x * 1024 + tid;
    int v = (i < N_NODES) ? deg[i] : 0;
    tmp[tid] = v;
    __syncthreads();
    #pragma unroll
    for (int o = 1; o < 1024; o <<= 1) {
        int t = (tid >= o) ? tmp[tid - o] : 0;
        __syncthreads();
        tmp[tid] += t;
        __syncthreads();
    }
    if (i < N_NODES) incl[i] = tmp[tid];
    if (tid == 1023) bsum[blockIdx.x] = tmp[1023];
}

__global__ void scan3_kernel(const int* __restrict__ deg, const int* __restrict__ incl,
                             const int* __restrict__ bsum,
                             int* __restrict__ off, int* __restrict__ cursor,
                             unsigned short* __restrict__ esrc)
{
    __shared__ int sb[NB_SCAN + 1];
    int tid = threadIdx.x;
    if (tid < 64) {
        int v = (tid < NB_SCAN) ? bsum[tid] : 0;
        int orig = v;
        #pragma unroll
        for (int o = 1; o < 64; o <<= 1) {
            int t = __shfl_up(v, o, 64);
            if (tid >= o) v += t;
        }
        if (tid < NB_SCAN) sb[tid] = v - orig;   // exclusive
        if (tid == 63)     sb[NB_SCAN] = v;      // grand total
    }
    __syncthreads();
    if (blockIdx.x == 0 && tid < 16) esrc[ET + tid] = 0;   // pad (safe over-reads)
    int i = blockIdx.x * blockDim.x + tid;
    if (i < N_NODES) {
        int e = incl[i] - deg[i] + sb[i >> 10];
        off[i] = e;
        cursor[i] = e;
    } else if (i == N_NODES) {
        off[N_NODES] = sb[NB_SCAN];
    }
}

// ===== MFMA dual GEMM, 1-term bf16, LDS-staged B + fused two-phase CSR scatter =======
// Scatter: edge loads in prologue; atomicAdds issued right after the MFMA loop (their
// latencies overlap the epilogue); dependent esrc stores at the very end.
template <bool WITH_SCATTER>
__global__ __launch_bounds__(256, 4)
void gemm_mfma_kernel(const unsigned short* __restrict__ hhi,
                      const unsigned short* __restrict__ wlh,
                      const unsigned short* __restrict__ wrh,
                      const float* __restrict__ bl, const float* __restrict__ br,
                      const float* __restrict__ att,
                      unsigned short* __restrict__ xlb, unsigned short* __restrict__ xrb,
                      float* __restrict__ bs2,
                      const int* __restrict__ srcp, const int* __restrict__ dstp,
                      int* __restrict__ cursor, unsigned short* __restrict__ esrc, int n)
{
    __shared__ unsigned short lb[64][BPAD];   // 17 KiB
    __shared__ unsigned short rb[64][BPAD];   // 17 KiB

    int tid  = threadIdx.x;
    int lane = tid & 63;
    int wid  = tid >> 6;                  // 0..3
    int rowB = blockIdx.x >> 1;
    int half = blockIdx.x & 1;
    int c0   = half * 64;                 // column half
    int m0   = rowB * 128 + wid * 32;     // this wave's 32 rows
    int gl = lane & 15;
    int kg = lane >> 4;

    // ---- scatter prologue: issue edge loads early ----
    int es[EPT], ed[EPT];
    if (WITH_SCATTER) {
        #pragma unroll
        for (int j = 0; j < EPT; j++) {
            int e = blockIdx.x * 256 + tid + j * SCAT_STRIDE;
            if (e < N_EDGES)      { es[j] = srcp[e]; ed[j] = dstp[e]; }
            else if (e < ET)      { es[j] = e - N_EDGES; ed[j] = es[j]; }
            else                  { es[j] = -1; ed[j] = -1; }
        }
    }

    // ---- stage B half into LDS (coalesced 16B chunks) ----
    {
        const uint4* gl4 = (const uint4*)(wlh + (size_t)c0 * D);
        const uint4* gr4 = (const uint4*)(wrh + (size_t)c0 * D);
        #pragma unroll
        for (int c = 0; c < 4; c++) {
            int idx = c * 256 + tid;
            int row = idx >> 4;
            int kc  = idx & 15;
            *(uint4*)&lb[row][kc * 8] = gl4[idx];
            *(uint4*)&rb[row][kc * 8] = gr4[idx];
        }
    }
    __syncthreads();

    float blc[4], brc[4], attc[4];
    #pragma unroll
    for (int t = 0; t < 4; t++) {
        blc[t]  = bl [c0 + t * 16 + gl];
        brc[t]  = br [c0 + t * 16 + gl];
        attc[t] = att[c0 + t * 16 + gl];
    }

    int ar0 = m0 + gl;      if (ar0 >= n) ar0 = n - 1;
    int ar1 = m0 + 16 + gl; if (ar1 >= n) ar1 = n - 1;
    const unsigned short* ah0 = hhi + (size_t)ar0 * D + kg * 8;
    const unsigned short* ah1 = hhi + (size_t)ar1 * D + kg * 8;

    bf16x8 Ah0[4], Ah1[4];
    #pragma unroll
    for (int ks = 0; ks < 4; ks++) {
        Ah0[ks] = *(const bf16x8*)(ah0 + ks * 32);
        Ah1[ks] = *(const bf16x8*)(ah1 + ks * 32);
    }

    f32x4 accl[2][4], accr[2][4];
    #pragma unroll
    for (int rt = 0; rt < 2; rt++)
        #pragma unroll
        for (int t = 0; t < 4; t++) {
            accl[rt][t] = (f32x4){0.f, 0.f, 0.f, 0.f};
            accr[rt][t] = (f32x4){0.f, 0.f, 0.f, 0.f};
        }

    #pragma unroll
    for (int ks = 0; ks < 4; ks++) {
        #pragma unroll
        for (int t = 0; t < 4; t++) {
            int brow = t * 16 + gl;
            int kofs = kg * 8 + ks * 32;
            bf16x8 bLH = *(const bf16x8*)&lb[brow][kofs];
            bf16x8 bRH = *(const bf16x8*)&rb[brow][kofs];
            accl[0][t] = __builtin_amdgcn_mfma_f32_16x16x32_bf16(Ah0[ks], bLH, accl[0][t], 0, 0, 0);
            accr[0][t] = __builtin_amdgcn_mfma_f32_16x16x32_bf16(Ah0[ks], bRH, accr[0][t], 0, 0, 0);
            accl[1][t] = __builtin_amdgcn_mfma_f32_16x16x32_bf16(Ah1[ks], bLH, accl[1][t], 0, 0, 0);
            accr[1][t] = __builtin_amdgcn_mfma_f32_16x16x32_bf16(Ah1[ks], bRH, accr[1][t], 0, 0, 0);
        }
    }

    // ---- scatter phase A: issue all independent atomics (latency overlaps epilogue) --
    int pos[EPT];
    if (WITH_SCATTER) {
        #pragma unroll
        for (int j = 0; j < EPT; j++)
            if (ed[j] >= 0) pos[j] = atomicAdd(cursor + ed[j], 1);
    }

    // ---- epilogue (C/D: col = lane&15, row = (lane>>4)*4 + reg) + bs half store ----
    #pragma unroll
    for (int rt = 0; rt < 2; rt++) {
        #pragma unroll
        for (int r = 0; r < 4; r++) {
            int row = m0 + rt * 16 + kg * 4 + r;
            if (row < n) {
                float p = 0.f;
                #pragma unroll
                for (int t = 0; t < 4; t++) {
                    int col = c0 + t * 16 + gl;
                    float vl = accl[rt][t][r] + blc[t];
                    xlb[(size_t)row * D + col] = f2bf_rne(vl);
                    xrb[(size_t)row * D + col] = f2bf_rne(accr[rt][t][r] + brc[t]);
                    p = fmaf(attc[t], vl, p);
                }
                p += __shfl_xor(p, 1, 64);
                p += __shfl_xor(p, 2, 64);
                p += __shfl_xor(p, 4, 64);
                p += __shfl_xor(p, 8, 64);
                if (gl == 0) bs2[row * 2 + half] = 0.6f * LOG2E * p;
            }
        }
    }

    // ---- scatter phase B: dependent esrc stores ----
    if (WITH_SCATTER) {
        #pragma unroll
        for (int j = 0; j < EPT; j++)
            if (ed[j] >= 0) esrc[pos[j]] = (unsigned short)es[j];
    }
}

// ===== fused per-node GATv2: 16 lanes/edge, 2 edges/group/iter, exp2-rebased =========
// score = bs2[s].x + bs2[s].y + sum(aav*|xl_s+xr_d|),  aav pre-scaled by 0.4*LOG2E.
template <int LAST>
__global__ void node_attn_kernel(const unsigned short* __restrict__ xlb,
                                 const unsigned short* __restrict__ xrb,
                                 const float* __restrict__ bs2,
                                 const float* __restrict__ att,
                                 const float* __restrict__ bias,
                                 const int* __restrict__ off,
                                 const unsigned short* __restrict__ esrc,
                                 float* __restrict__ outF,
                                 unsigned short* __restrict__ hhi)
{
    int i    = (int)((blockIdx.x * (size_t)blockDim.x + threadIdx.x) >> 6);
    int lane = threadIdx.x & 63;
    if (i >= N_NODES) return;
    int g  = lane >> 4;     // edge-pair slot 0..3
    int gl = lane & 15;     // lane within group
    int fb = gl * 8;        // this lane's 8 features

    float aav[8];
    f32x2 rr2[4];
    {
        float4 a0 = *(const float4*)(att + fb);
        float4 a1 = *(const float4*)(att + fb + 4);
        const float s = 0.4f * LOG2E;
        aav[0] = s * a0.x; aav[1] = s * a0.y; aav[2] = s * a0.z; aav[3] = s * a0.w;
        aav[4] = s * a1.x; aav[5] = s * a1.y; aav[6] = s * a1.z; aav[7] = s * a1.w;
        uint4 r4 = *(const uint4*)(xrb + (size_t)i * D + fb);
        rr2[0] = unpack_bf2(r4.x); rr2[1] = unpack_bf2(r4.y);
        rr2[2] = unpack_bf2(r4.z); rr2[3] = unpack_bf2(r4.w);
    }

    float m = -1e30f, l = 0.f;
    f32x2 acc2[4];
    #pragma unroll
    for (int j = 0; j < 4; j++) acc2[j] = (f32x2){0.f, 0.f};

    int k    = off[i];
    int kEnd = off[i + 1];

    int ka = k + g, kb = k + 4 + g;
    bool va = ka < kEnd, vb = kb < kEnd;
    int sa = esrc[ka];                      // padded: over-read safe
    int sb = esrc[kb];
    uint4 x4a = *(const uint4*)(xlb + (size_t)sa * D + fb);
    uint4 x4b = *(const uint4*)(xlb + (size_t)sb * D + fb);
    float2 ba2 = *(const float2*)(bs2 + sa * 2);
    float2 bb2 = *(const float2*)(bs2 + sb * 2);
    float bsa = ba2.x + ba2.y, bsb = bb2.x + bb2.y;

    while (k < kEnd) {
        int kn = k + 8;
        uint4 nxa = x4a, nxb = x4b;
        float nbsa = bsa, nbsb = bsb;
        bool nva = false, nvb = false;
        if (kn < kEnd) {                    // wave-uniform prefetch
            int nka = kn + g, nkb = kn + 4 + g;
            nva = nka < kEnd; nvb = nkb < kEnd;
            int nsa = esrc[nka];
            int nsb = esrc[nkb];
            nxa = *(const uint4*)(xlb + (size_t)nsa * D + fb);
            nxb = *(const uint4*)(xlb + (size_t)nsb * D + fb);
            float2 na2 = *(const float2*)(bs2 + nsa * 2);
            float2 nb2 = *(const float2*)(bs2 + nsb * 2);
            nbsa = na2.x + na2.y; nbsb = nb2.x + nb2.y;
        }
        f32x2 xa2[4], xb2[4];
        xa2[0] = unpack_bf2(x4a.x); xa2[1] = unpack_bf2(x4a.y);
        xa2[2] = unpack_bf2(x4a.z); xa2[3] = unpack_bf2(x4a.w);
        xb2[0] = unpack_bf2(x4b.x); xb2[1] = unpack_bf2(x4b.y);
        xb2[2] = unpack_bf2(x4b.z); xb2[3] = unpack_bf2(x4b.w);

        float s2a = 0.f, s2b = 0.f;
        #pragma unroll
        for (int q = 0; q < 4; q++) {
            f32x2 ta = xa2[q] + rr2[q];      // v_pk_add_f32
            f32x2 tb = xb2[q] + rr2[q];
            s2a = fmaf(aav[2*q],   fabsf(ta.x), s2a);
            s2a = fmaf(aav[2*q+1], fabsf(ta.y), s2a);
            s2b = fmaf(aav[2*q],   fabsf(tb.x), s2b);
            s2b = fmaf(aav[2*q+1], fabsf(tb.y), s2b);
        }
        s2a += __shfl_xor(s2a, 1, 64);
        s2b += __shfl_xor(s2b, 1, 64);
        s2a += __shfl_xor(s2a, 2, 64);
        s2b += __shfl_xor(s2b, 2, 64);
        s2a += __shfl_xor(s2a, 4, 64);
        s2b += __shfl_xor(s2b, 4, 64);
        s2a += __shfl_xor(s2a, 8, 64);
        s2b += __shfl_xor(s2b, 8, 64);
        float sca = bsa + s2a;
        float scb = bsb + s2b;
        float mx2 = fmaxf(sca, scb);
        if (__any(mx2 > m + DEFER_THR)) {
            float mn = fmaxf(m, mx2);
            float f  = exp2f(m - mn);
            float pa = va ? exp2f(sca - mn) : 0.f;
            float pb = vb ? exp2f(scb - mn) : 0.f;
            l = l * f + pa + pb;
            f32x2 fv = {f, f}, pa2 = {pa, pa}, pb2 = {pb, pb};
            #pragma unroll
            for (int q = 0; q < 4; q++)
                acc2[q] = __builtin_elementwise_fma(acc2[q], fv,
                          __builtin_elementwise_fma(xa2[q], pa2, xb2[q] * pb2));
            m = mn;
        } else {
            float pa = va ? exp2f(sca - m) : 0.f;
            float pb = vb ? exp2f(scb - m) : 0.f;
            l += pa + pb;
            f32x2 pa2 = {pa, pa}, pb2 = {pb, pb};
            #pragma unroll
            for (int q = 0; q < 4; q++)
                acc2[q] = __builtin_elementwise_fma(xa2[q], pa2,
                          __builtin_elementwise_fma(xb2[q], pb2, acc2[q]));
        }
        x4a = nxa; x4b = nxb; bsa = nbsa; bsb = nbsb; va = nva; vb = nvb;
        k = kn;
    }

    // merge the 4 groups' online-softmax states (xor 16, then 32), log2 units
    #pragma unroll
    for (int o = 16; o <= 32; o <<= 1) {
        float mo  = __shfl_xor(m, o, 64);
        float lo2 = __shfl_xor(l, o, 64);
        float mn  = fmaxf(m, mo);
        float f1  = exp2f(m - mn);
        float f2s = exp2f(mo - mn);
        l = l * f1 + lo2 * f2s;
        f32x2 f1v = {f1, f1}, f2v = {f2s, f2s};
        #pragma unroll
        for (int q = 0; q < 4; q++) {
            f32x2 ao;
            ao.x = __shfl_xor(acc2[q].x, o, 64);
            ao.y = __shfl_xor(acc2[q].y, o, 64);
            acc2[q] = __builtin_elementwise_fma(acc2[q], f1v, ao * f2v);
        }
        m = mn;
    }

    float inv = 1.f / (l + 1e-16f);
    float hv[8];
    {
        float4 b0 = *(const float4*)(bias + fb);
        float4 b1 = *(const float4*)(bias + fb + 4);
        float bb[8] = {b0.x, b0.y, b0.z, b0.w, b1.x, b1.y, b1.z, b1.w};
        #pragma unroll
        for (int q = 0; q < 4; q++) {
            hv[2*q]   = fmaxf(fmaf(acc2[q].x, inv, bb[2*q]),   0.f);
            hv[2*q+1] = fmaxf(fmaf(acc2[q].y, inv, bb[2*q+1]), 0.f);
        }
    }

    if (LAST) {
        float mx = hv[0];
        #pragma unroll
        for (int j = 1; j < 8; j++) mx = fmaxf(mx, hv[j]);
        mx = fmaxf(mx, __shfl_xor(mx, 1, 64));
        mx = fmaxf(mx, __shfl_xor(mx, 2, 64));
        mx = fmaxf(mx, __shfl_xor(mx, 4, 64));
        mx = fmaxf(mx, __shfl_xor(mx, 8, 64));
        float se = 0.f;
        #pragma unroll
        for (int j = 0; j < 8; j++) se += __expf(hv[j] - mx);
        se += __shfl_xor(se, 1, 64);
        se += __shfl_xor(se, 2, 64);
        se += __shfl_xor(se, 4, 64);
        se += __shfl_xor(se, 8, 64);
        float ls = logf(se) + mx;
        if (g == 0) {
            float4 o0 = make_float4(hv[0] - ls, hv[1] - ls, hv[2] - ls, hv[3] - ls);
            float4 o1 = make_float4(hv[4] - ls, hv[5] - ls, hv[6] - ls, hv[7] - ls);
            float* dst = outF + (size_t)i * D + fb;
            *(float4*)(dst)     = o0;
            *(float4*)(dst + 4) = o1;
        }
    } else {
        if (g == 0) {
            unsigned pk[4];
            #pragma unroll
            for (int j = 0; j < 4; j++) {
                pk[j] = (unsigned)f2bf_rne(hv[j * 2]) |
                        ((unsigned)f2bf_rne(hv[j * 2 + 1]) << 16);
            }
            unsigned short* dst = hhi + (size_t)i * D + fb;
            *(uint4*)dst = make_uint4(pk[0], pk[1], pk[2], pk[3]);
        }
    }
}

extern "C" void kernel_launch(void* const* d_in, const int* in_sizes, int n_in,
                              void* d_out, int out_size, void* d_ws, size_t ws_size,
                              hipStream_t stream)
{
    const float* x    = (const float*)d_in[0];
    const int*   ei   = (const int*)  d_in[1];
    const float* Wl   = (const float*)d_in[2];
    const float* bl   = (const float*)d_in[3];
    const float* Wr   = (const float*)d_in[4];
    const float* br   = (const float*)d_in[5];
    const float* att  = (const float*)d_in[6];
    const float* bias = (const float*)d_in[7];
    float* out = (float*)d_out;

    const int* srcp = ei;
    const int* dstp = ei + N_EDGES;

    const size_t ND = (size_t)N_NODES * D;
    const size_t WSZ = (size_t)NLAYERS * D * D;
    char* ws = (char*)d_ws;
    unsigned short* xlb = (unsigned short*)ws; ws += ND * sizeof(unsigned short);
    unsigned short* xrb = (unsigned short*)ws; ws += ND * sizeof(unsigned short);
    unsigned short* hhi = (unsigned short*)ws; ws += ND * sizeof(unsigned short);
    unsigned short* wlh = (unsigned short*)ws; ws += WSZ * sizeof(unsigned short);
    unsigned short* wrh = (unsigned short*)ws; ws += WSZ * sizeof(unsigned short);
    float* bs2  = (float*)ws; ws += (size_t)N_NODES * 2 * sizeof(float);
    int* deg    = (int*)ws;  ws += (size_t)N_NODES * sizeof(int);
    int* incl   = (int*)ws;  ws += (size_t)N_NODES * sizeof(int);
    int* off    = (int*)ws;  ws += (size_t)(N_NODES + 1) * sizeof(int);
    int* cursor = (int*)ws;  ws += (size_t)N_NODES * sizeof(int);
    int* bsum   = (int*)ws;  ws += (size_t)NB_SCAN * sizeof(int);
    unsigned short* esrc = (unsigned short*)ws; ws += ((size_t)ET + 16) * sizeof(unsigned short);

    const int prepGrid  = (int)((ND / 4 + 255) / 256);
    const int nodeGrid  = (N_NODES + 3) / 4;
    const int scan3Grid = (N_NODES + 1 + 255) / 256;

    hipMemsetAsync(deg, 0, (size_t)N_NODES * sizeof(int), stream);
    prep_kernel<<<prepGrid, 256, 0, stream>>>(x, Wl, Wr, dstp, hhi, wlh, wrh, deg);

    scan1_kernel<<<NB_SCAN, 1024, 0, stream>>>(deg, incl, bsum);
    scan3_kernel<<<scan3Grid, 256, 0, stream>>>(deg, incl, bsum, off, cursor, esrc);

    for (int l = 0; l < NLAYERS; l++) {
        size_t wOff = (size_t)l * D * D;
        if (l == 0) {
            gemm_mfma_kernel<true><<<GEMM_BLOCKS, 256, 0, stream>>>(
                hhi, wlh + wOff, wrh + wOff,
                bl + (size_t)l * D, br + (size_t)l * D, att + (size_t)l * D,
                xlb, xrb, bs2, srcp, dstp, cursor, esrc, N_NODES);
        } else {
            gemm_mfma_kernel<false><<<GEMM_BLOCKS, 256, 0, stream>>>(
                hhi, wlh + wOff, wrh + wOff,
                bl + (size_t)l * D, br + (size_t)l * D, att + (size_t)l * D,
                xlb, xrb, bs2, nullptr, nullptr, nullptr, nullptr, N_NODES);
        }

        if (l == NLAYERS - 1) {
            node_attn_kernel<1><<<nodeGrid, 256, 0, stream>>>(
                xlb, xrb, bs2, att + (size_t)l * D, bias + (size_t)l * D,
                off, esrc, out, nullptr);
        } else {
            node_attn_kernel<0><<<nodeGrid, 256, 0, stream>>>(
                xlb, xrb, bs2, att + (size_t)l * D, bias + (size_t)l * D,
                off, esrc, nullptr, hhi);
        }
    }
}